// Round 2
// baseline (112372.339 us; speedup 1.0000x reference)
//
#include <hip/hip_runtime.h>
#include <hip/hip_bf16.h>

typedef __attribute__((ext_vector_type(8))) short short8;
typedef __attribute__((ext_vector_type(4))) float f32x4;
typedef __hip_bfloat16 bf16;

#define NB 256
#define NT 256
#define TSTEPS 512

__device__ inline short f2bf(float v) {
    bf16 h = __float2bfloat16(v);
    return *reinterpret_cast<short*>(&h);
}

// ---------------------------------------------------------------------------
// Manual grid barrier (device/agent scope). All NB blocks are provably
// co-resident: __launch_bounds__(256,2) => VGPR<=128 => >=2 blocks/CU => cap
// 512 >= NB=256, so no block waits for dispatch. __threadfence() emits the
// gfx950 agent-scope L2 writeback/invalidate needed for cross-XCD visibility
// (same mechanism cg::grid.sync() uses).
// ---------------------------------------------------------------------------
__device__ __forceinline__ void gbar(int* cnt, int* sns, int& phase) {
    __syncthreads();                       // all waves' stores drained (vmcnt)
    if (threadIdx.x == 0) {
        __threadfence();                   // release: write back dirty L2
        const int p = phase + 1;
        if (__hip_atomic_fetch_add(cnt, 1, __ATOMIC_ACQ_REL, __HIP_MEMORY_SCOPE_AGENT) == NB - 1) {
            __hip_atomic_store(cnt, 0, __ATOMIC_RELAXED, __HIP_MEMORY_SCOPE_AGENT);
            __hip_atomic_store(sns, p, __ATOMIC_RELEASE, __HIP_MEMORY_SCOPE_AGENT);
        } else {
            while (__hip_atomic_load(sns, __ATOMIC_ACQUIRE, __HIP_MEMORY_SCOPE_AGENT) < p) {
                __builtin_amdgcn_s_sleep(2);
            }
        }
        __threadfence();                   // acquire: invalidate stale L1/L2
    }
    ++phase;
    __syncthreads();
}

// ---------------------------------------------------------------------------
// 64x64 output-tile BT-GEMM, bf16 A and B: C[m0:+64, n0:+64] (+)= A @ B^T
// over K-chunks [c0,c1) of 64. LDS XOR-swizzled (G4). Register prefetch of
// the next chunk's operands overlaps global load latency with MFMA (T14).
// MFMA 16x16x32 bf16; C/D: col=lane&15, row=(lane>>4)*4+reg (m89-verified).
// ---------------------------------------------------------------------------
template<bool ATOMIC>
__device__ void gemm64_bf(const bf16* __restrict__ A, int lda,
                          const bf16* __restrict__ B, int ldb,
                          float* __restrict__ C, long ldc, int m0, int n0,
                          int c0, int c1, char* ldsA, char* ldsB)
{
    const int tid = threadIdx.x, wave = tid >> 6, lane = tid & 63;
    const int r15 = lane & 15, kg = lane >> 4;
    const int s1 = tid + 256;
    const int row0 = tid >> 3, cg0 = tid & 7;
    const int row1 = s1 >> 3,  cg1 = s1 & 7;
    const int lb0 = (tid * 16) ^ ((row0 & 7) << 4);
    const int lb1 = (s1 * 16)  ^ ((row1 & 7) << 4);
    const bf16* a0 = A + (size_t)(m0 + row0) * lda + cg0 * 8;
    const bf16* a1 = A + (size_t)(m0 + row1) * lda + cg1 * 8;
    const bf16* b0 = B + (size_t)(n0 + row0) * ldb + cg0 * 8;
    const bf16* b1 = B + (size_t)(n0 + row1) * ldb + cg1 * 8;

    f32x4 acc[4];
#pragma unroll
    for (int i = 0; i < 4; ++i) acc[i] = (f32x4){0.f, 0.f, 0.f, 0.f};

    short8 pa0 = *(const short8*)(a0 + (size_t)c0 * 64);
    short8 pa1 = *(const short8*)(a1 + (size_t)c0 * 64);
    short8 pb0 = *(const short8*)(b0 + (size_t)c0 * 64);
    short8 pb1 = *(const short8*)(b1 + (size_t)c0 * 64);

    for (int c = c0; c < c1; ++c) {
        __syncthreads();                       // previous chunk's readers done
        *(short8*)(ldsA + lb0) = pa0;
        *(short8*)(ldsA + lb1) = pa1;
        *(short8*)(ldsB + lb0) = pb0;
        *(short8*)(ldsB + lb1) = pb1;
        const int cn = (c + 1 < c1) ? c + 1 : c;   // clamped prefetch
        pa0 = *(const short8*)(a0 + (size_t)cn * 64);
        pa1 = *(const short8*)(a1 + (size_t)cn * 64);
        pb0 = *(const short8*)(b0 + (size_t)cn * 64);
        pb1 = *(const short8*)(b1 + (size_t)cn * 64);
        __syncthreads();
        const int bro = wave * 16 + r15;
        const int bsz = (bro & 7) << 4;
#pragma unroll
        for (int kk = 0; kk < 2; ++kk) {
            short8 bfr = *(short8*)(ldsB + ((bro * 128 + (kg + kk * 4) * 16) ^ bsz));
#pragma unroll
            for (int mf = 0; mf < 4; ++mf) {
                int aro = mf * 16 + r15;
                short8 afr = *(short8*)(ldsA + ((aro * 128 + (kg + kk * 4) * 16) ^ ((aro & 7) << 4)));
                acc[mf] = __builtin_amdgcn_mfma_f32_16x16x32_bf16(afr, bfr, acc[mf], 0, 0, 0);
            }
        }
    }

    const int col = lane & 15, rg = lane >> 4;
#pragma unroll
    for (int mf = 0; mf < 4; ++mf)
#pragma unroll
        for (int r = 0; r < 4; ++r) {
            long m = m0 + mf * 16 + rg * 4 + r;
            long n = n0 + wave * 16 + col;
            if constexpr (ATOMIC) atomicAdd(&C[m * ldc + n], acc[mf][r]);
            else                  C[m * ldc + n] = acc[mf][r];
        }
}

// Same tile, but A is f32 (converted to bf16 during staging). K fixed = 256.
__device__ void gemm64_f32A(const float* __restrict__ A, int lda,
                            const bf16* __restrict__ B, int ldb,
                            float* __restrict__ C, int ldc, int m0, int n0,
                            char* ldsA, char* ldsB)
{
    const int tid = threadIdx.x, wave = tid >> 6, lane = tid & 63;
    const int r15 = lane & 15, kg = lane >> 4;
    f32x4 acc[4];
#pragma unroll
    for (int i = 0; i < 4; ++i) acc[i] = (f32x4){0.f, 0.f, 0.f, 0.f};

    for (int c = 0; c < 4; ++c) {
        const int k0 = c << 6;
        __syncthreads();
#pragma unroll
        for (int it = 0; it < 2; ++it) {
            int s = it * 256 + tid;
            int row = s >> 3, cgp = s & 7;
            int lb = (s * 16) ^ ((row & 7) << 4);
            const float* ap = A + (size_t)(m0 + row) * lda + k0 + cgp * 8;
            short8 o;
#pragma unroll
            for (int q = 0; q < 8; ++q) o[q] = f2bf(ap[q]);
            *(short8*)(ldsA + lb) = o;
            *(short8*)(ldsB + lb) = *(const short8*)(B + (size_t)(n0 + row) * ldb + k0 + cgp * 8);
        }
        __syncthreads();
        const int bro = wave * 16 + r15;
        const int bsz = (bro & 7) << 4;
#pragma unroll
        for (int kk = 0; kk < 2; ++kk) {
            short8 bfr = *(short8*)(ldsB + ((bro * 128 + (kg + kk * 4) * 16) ^ bsz));
#pragma unroll
            for (int mf = 0; mf < 4; ++mf) {
                int aro = mf * 16 + r15;
                short8 afr = *(short8*)(ldsA + ((aro * 128 + (kg + kk * 4) * 16) ^ ((aro & 7) << 4)));
                acc[mf] = __builtin_amdgcn_mfma_f32_16x16x32_bf16(afr, bfr, acc[mf], 0, 0, 0);
            }
        }
    }
    const int col = lane & 15, rg = lane >> 4;
#pragma unroll
    for (int mf = 0; mf < 4; ++mf)
#pragma unroll
        for (int r = 0; r < 4; ++r) {
            int m = m0 + mf * 16 + rg * 4 + r;
            int n = n0 + wave * 16 + col;
            C[(size_t)m * ldc + n] = acc[mf][r];
        }
}

// ---------------------------------------------------------------------------
// Prep kernels
// ---------------------------------------------------------------------------
__global__ void prep_transpose(const float* __restrict__ cond, const float* __restrict__ zs,
                               float* __restrict__ condT, float* __restrict__ zsT,
                               int* bstate, float* dout) {
    int i = blockIdx.x * 256 + threadIdx.x;
    if (i < 128 * 256) {
        int b = i >> 8, c = i & 255;
        condT[c * 128 + b] = cond[i];
        zsT[c * 128 + b]   = zs[i];
    }
    if (blockIdx.x == 0 && threadIdx.x < 64) bstate[threadIdx.x] = 0;  // barrier state
    if (blockIdx.x == 0 && threadIdx.x == 0) dout[0] = 12345.0f;       // sentinel
}

__global__ void prep_wcvt(const float* __restrict__ whh1, const float* __restrict__ wih2,
                          const float* __restrict__ whh2, const float* __restrict__ wih1,
                          const float* __restrict__ headw,
                          bf16* whh1b, bf16* wih2b, bf16* whh2b, bf16* w1xb, bf16* headb) {
    int gs = gridDim.x * blockDim.x;
    for (int i = blockIdx.x * blockDim.x + threadIdx.x; i < 3072 * 1024; i += gs) {
        whh1b[i] = __float2bfloat16(whh1[i]);
        wih2b[i] = __float2bfloat16(wih2[i]);
        whh2b[i] = __float2bfloat16(whh2[i]);
    }
    for (int i = blockIdx.x * blockDim.x + threadIdx.x; i < 3072 * 256; i += gs) {
        int g = i >> 8, k = i & 255;
        w1xb[i] = __float2bfloat16(wih1[g * 512 + k]);   // w_ih1[:, :256]
    }
    for (int i = blockIdx.x * blockDim.x + threadIdx.x; i < 256 * 1024; i += gs) {
        headb[i] = __float2bfloat16(headw[i]);
    }
}

__global__ void prep_cond(const float* __restrict__ condT, const float* __restrict__ wih1,
                          const float* __restrict__ bih1, const float* __restrict__ filmw,
                          const float* __restrict__ filmb,
                          float* const1, float* scale, float* beta) {
    int gs = gridDim.x * blockDim.x;
    for (int idx = blockIdx.x * blockDim.x + threadIdx.x; idx < 128 * 3072; idx += gs) {
        int b = idx & 127, g = idx >> 7;
        float acc = bih1[g];
        for (int c = 0; c < 256; ++c) acc += condT[c * 128 + b] * wih1[g * 512 + 256 + c];
        const1[b * 3072 + g] = acc;
    }
    for (int idx = blockIdx.x * blockDim.x + threadIdx.x; idx < 128 * 2048; idx += gs) {
        int b = idx & 127, jj = idx >> 7;
        float acc = filmb[jj];
        for (int c = 0; c < 256; ++c) acc += condT[c * 128 + b] * filmw[jj * 256 + c];
        if (jj < 1024) scale[b * 1024 + jj] = 1.f + acc;
        else           beta[b * 1024 + (jj - 1024)] = acc;
    }
}

__global__ void prep_h0a(const float* __restrict__ zsT, const float* __restrict__ w1,
                         const float* __restrict__ b1, float* __restrict__ L1T) {
    int idx = blockIdx.x * 256 + threadIdx.x;
    if (idx >= 128 * 1024) return;
    int b = idx & 127, j = idx >> 7;
    float acc = b1[j];
    for (int k = 0; k < 256; ++k) acc += zsT[k * 128 + b] * w1[j * 256 + k];
    L1T[j * 128 + b] = fmaxf(acc, 0.f);
}

__global__ void prep_h0b(const float* __restrict__ L1T, const float* __restrict__ w2,
                         const float* __restrict__ b2,
                         float* h1, float* h2, bf16* hb1, bf16* hb2) {
    int idx = blockIdx.x * 256 + threadIdx.x;
    if (idx >= 128 * 1024) return;
    int b = idx & 127, j = idx >> 7;
    float acc = b2[j];
    for (int k = 0; k < 1024; ++k) acc += L1T[k * 128 + b] * w2[j * 1024 + k];
    h1[b * 1024 + j] = acc;
    h2[b * 1024 + j] = acc;
    bf16 hv = __float2bfloat16(acc);
    hb1[b * 1024 + j] = hv;
    hb2[b * 1024 + j] = hv;
}

// ---------------------------------------------------------------------------
// Persistent rollout: 5 phases/step, manual grid barrier between phases.
// ---------------------------------------------------------------------------
struct RArgs {
    const float* zs;
    const float* bhh1; const float* bih2; const float* bhh2; const float* headbias;
    float* const1; float* scale; float* beta;
    float* h1; float* h2; float* zbuf;
    float* bufP; float* bufQ; float* bufR; float* bufS;   // bufS = 2 partials
    bf16* hb1; bf16* hb2; bf16* yb;
    const bf16* whh1b; const bf16* wih2b; const bf16* whh2b; const bf16* w1xb; const bf16* headb;
    float* dout;
    int* bstate;
};

__global__ __launch_bounds__(NT, 2) void rollout(RArgs a) {
    __shared__ char lds[16384];
    char* ldsA = lds;
    char* ldsB = lds + 8192;
    const int u   = blockIdx.x;
    const int tid = threadIdx.x;
    const int gsz = NB * NT;
    const int gt  = u * NT + tid;
    int* cnt = a.bstate;
    int* sns = a.bstate + 32;
    int phase = 0;

    for (int t = 0; t < TSTEPS; ++t) {
        // ---- P1: bufQ = h1@whh1^T (96), bufR = h2@whh2^T (96), bufP = x@w1x^T (64)
        if (u < 96) {
            gemm64_bf<false>(a.hb1, 1024, a.whh1b, 1024, a.bufQ, 3072,
                             (u & 1) * 64, (u >> 1) * 64, 0, 16, ldsA, ldsB);
        } else if (u < 192) {
            int v = u - 96;
            gemm64_bf<false>(a.hb2, 1024, a.whh2b, 1024, a.bufR, 3072,
                             (v & 1) * 64, (v >> 1) * 64, 0, 16, ldsA, ldsB);
        } else {
            int v = u - 192;                         // 64 blocks cover 96 tiles
            const float* zsrc = (t == 0) ? a.zs : a.zbuf;
            gemm64_f32A(zsrc, 256, a.w1xb, 256, a.bufP, 3072,
                        (v & 1) * 64, (v >> 1) * 64, ldsA, ldsB);
            if (v < 32) {
                int w = v + 64;
                gemm64_f32A(zsrc, 256, a.w1xb, 256, a.bufP, 3072,
                            (w & 1) * 64, (w >> 1) * 64, ldsA, ldsB);
            }
        }
        gbar(cnt, sns, phase);

        // ---- P2: GRU1 combine -> h1, hb1 ; write outs[t-1]
        for (int e = gt; e < 128 * 1024; e += gsz) {
            int b = e >> 10, j = e & 1023;
            const float* bp = a.bufP + b * 3072;
            const float* bq = a.bufQ + b * 3072;
            const float* c1 = a.const1 + b * 3072;
            float ir  = bp[j]        + c1[j];
            float iz  = bp[j + 1024] + c1[j + 1024];
            float in_ = bp[j + 2048] + c1[j + 2048];
            float hr  = bq[j]        + a.bhh1[j];
            float hz  = bq[j + 1024] + a.bhh1[j + 1024];
            float hn  = bq[j + 2048] + a.bhh1[j + 2048];
            float r = 1.f / (1.f + __expf(-(ir + hr)));
            float z = 1.f / (1.f + __expf(-(iz + hz)));
            float n = tanhf(in_ + r * hn);
            float hp = (1.f - z) * n + z * a.h1[e];
            a.h1[e]  = hp;
            a.hb1[e] = __float2bfloat16(hp);
        }
        if (t > 0) {
            for (int e = gt; e < 128 * 256; e += gsz) {
                int b = e >> 8, l = e & 255;
                a.dout[(size_t)b * 131072 + (size_t)(t - 1) * 256 + l] = a.zbuf[e];
            }
        }
        gbar(cnt, sns, phase);

        // ---- P3: bufS[ks] = h1'@wih2^T partials (96 tiles x 2 K-splits, non-atomic)
        if (u < 192) {
            int tu = u >> 1, ks = u & 1;
            gemm64_bf<false>(a.hb1, 1024, a.wih2b, 1024, a.bufS + (size_t)ks * 393216, 3072,
                             (tu & 1) * 64, (tu >> 1) * 64, ks * 8, ks * 8 + 8, ldsA, ldsB);
        }
        gbar(cnt, sns, phase);

        // ---- P4: GRU2 combine -> h2, hb2, y(bf16) ; zbuf = head bias
        for (int e = gt; e < 128 * 1024; e += gsz) {
            int b = e >> 10, j = e & 1023;
            const float* bs0 = a.bufS + b * 3072;
            const float* bs1 = a.bufS + 393216 + b * 3072;
            const float* br  = a.bufR + b * 3072;
            float ir  = bs0[j]        + bs1[j]        + a.bih2[j];
            float iz  = bs0[j + 1024] + bs1[j + 1024] + a.bih2[j + 1024];
            float in_ = bs0[j + 2048] + bs1[j + 2048] + a.bih2[j + 2048];
            float hr  = br[j]        + a.bhh2[j];
            float hz  = br[j + 1024] + a.bhh2[j + 1024];
            float hn  = br[j + 2048] + a.bhh2[j + 2048];
            float r = 1.f / (1.f + __expf(-(ir + hr)));
            float z = 1.f / (1.f + __expf(-(iz + hz)));
            float n = tanhf(in_ + r * hn);
            float hp = (1.f - z) * n + z * a.h2[e];
            a.h2[e]  = hp;
            a.hb2[e] = __float2bfloat16(hp);
            float y = a.scale[e] * hp + a.beta[e];
            a.yb[e] = __float2bfloat16(y);
        }
        for (int e = gt; e < 128 * 256; e += gsz) a.zbuf[e] = a.headbias[e & 255];
        gbar(cnt, sns, phase);

        // ---- P5: zbuf += y@head^T (8 tiles x 4 K-splits = 32 units, atomic)
        if (u < 32) {
            int ks = u >> 3, v = u & 7;
            gemm64_bf<true>(a.yb, 1024, a.headb, 1024, a.zbuf, 256,
                            (v & 1) * 64, (v >> 1) * 64, ks * 4, ks * 4 + 4, ldsA, ldsB);
        }
        gbar(cnt, sns, phase);
    }

    // final output row t=511
    for (int e = gt; e < 128 * 256; e += gsz) {
        int b = e >> 8, l = e & 255;
        a.dout[(size_t)b * 131072 + (size_t)511 * 256 + l] = a.zbuf[e];
    }
}

// ---------------------------------------------------------------------------
extern "C" void kernel_launch(void* const* d_in, const int* in_sizes, int n_in,
                              void* d_out, int out_size, void* d_ws, size_t ws_size,
                              hipStream_t stream) {
    const float* zs       = (const float*)d_in[0];
    const float* cond     = (const float*)d_in[1];
    // d_in[2] = max_len (fixed 512)
    const float* z2hw1    = (const float*)d_in[3];
    const float* z2hb1    = (const float*)d_in[4];
    const float* z2hw2    = (const float*)d_in[5];
    const float* z2hb2    = (const float*)d_in[6];
    const float* wih1     = (const float*)d_in[7];
    const float* whh1     = (const float*)d_in[8];
    const float* bih1     = (const float*)d_in[9];
    const float* bhh1     = (const float*)d_in[10];
    const float* wih2     = (const float*)d_in[11];
    const float* whh2     = (const float*)d_in[12];
    const float* bih2     = (const float*)d_in[13];
    const float* bhh2     = (const float*)d_in[14];
    const float* filmw    = (const float*)d_in[15];
    const float* filmb    = (const float*)d_in[16];
    const float* headw    = (const float*)d_in[17];
    const float* headbias = (const float*)d_in[18];

    char* p = (char*)d_ws;
    auto alloc = [&](size_t bytes) {
        char* r = p;
        p += (bytes + 255) & ~(size_t)255;
        return r;
    };
    int*  bstate  = (int*)alloc(256);
    bf16* whh1b   = (bf16*)alloc(3072 * 1024 * 2);
    bf16* wih2b   = (bf16*)alloc(3072 * 1024 * 2);
    bf16* whh2b   = (bf16*)alloc(3072 * 1024 * 2);
    bf16* w1xb    = (bf16*)alloc(3072 * 256 * 2);
    bf16* headb   = (bf16*)alloc(256 * 1024 * 2);
    float* const1 = (float*)alloc(128 * 3072 * 4);
    float* scale  = (float*)alloc(128 * 1024 * 4);
    float* beta   = (float*)alloc(128 * 1024 * 4);
    float* h1     = (float*)alloc(128 * 1024 * 4);
    float* h2     = (float*)alloc(128 * 1024 * 4);
    float* zbuf   = (float*)alloc(128 * 256 * 4);
    float* bufP   = (float*)alloc(128 * 3072 * 4);
    float* bufQ   = (float*)alloc(128 * 3072 * 4);
    float* bufR   = (float*)alloc(128 * 3072 * 4);
    float* bufS   = (float*)alloc(2 * 128 * 3072 * 4);   // two K-split partials
    bf16* hb1     = (bf16*)alloc(128 * 1024 * 2);
    bf16* hb2     = (bf16*)alloc(128 * 1024 * 2);
    bf16* yb      = (bf16*)alloc(128 * 1024 * 2);
    float* condT  = (float*)alloc(128 * 256 * 4);
    float* zsT    = (float*)alloc(128 * 256 * 4);
    float* L1T    = (float*)alloc(128 * 1024 * 4);
    // total ~34 MiB of d_ws

    prep_transpose<<<dim3(128), dim3(256), 0, stream>>>(cond, zs, condT, zsT, bstate, (float*)d_out);
    prep_wcvt<<<dim3(1024), dim3(256), 0, stream>>>(whh1, wih2, whh2, wih1, headw,
                                                    whh1b, wih2b, whh2b, w1xb, headb);
    prep_cond<<<dim3(1536), dim3(256), 0, stream>>>(condT, wih1, bih1, filmw, filmb,
                                                    const1, scale, beta);
    prep_h0a<<<dim3(512), dim3(256), 0, stream>>>(zsT, z2hw1, z2hb1, L1T);
    prep_h0b<<<dim3(512), dim3(256), 0, stream>>>(L1T, z2hw2, z2hb2, h1, h2, hb1, hb2);

    RArgs ra;
    ra.zs = zs; ra.bhh1 = bhh1; ra.bih2 = bih2; ra.bhh2 = bhh2; ra.headbias = headbias;
    ra.const1 = const1; ra.scale = scale; ra.beta = beta;
    ra.h1 = h1; ra.h2 = h2; ra.zbuf = zbuf;
    ra.bufP = bufP; ra.bufQ = bufQ; ra.bufR = bufR; ra.bufS = bufS;
    ra.hb1 = hb1; ra.hb2 = hb2; ra.yb = yb;
    ra.whh1b = whh1b; ra.wih2b = wih2b; ra.whh2b = whh2b; ra.w1xb = w1xb; ra.headb = headb;
    ra.dout = (float*)d_out;
    ra.bstate = bstate;

    rollout<<<dim3(NB), dim3(NT), 0, stream>>>(ra);
}

// Round 3
// 43902.975 us; speedup vs baseline: 2.5596x; 2.5596x over previous
//
#include <hip/hip_runtime.h>
#include <hip/hip_bf16.h>

typedef __attribute__((ext_vector_type(8))) short short8;
typedef __attribute__((ext_vector_type(4))) float f32x4;
typedef __hip_bfloat16 bf16;
typedef unsigned long long ull;

#define NB 256
#define NT 256
#define TSTEPS 512
#define GRPS 8
#define GSIZE (NB / GRPS)

// ---------------------------------------------------------------------------
// Coherence protocol (no L2 invalidation — keeps weights L2-resident):
//  - intra-kernel cross-block data is READ via relaxed system-scope atomic
//    loads (sc0 sc1: bypass L1/L2, read the coherence point / L3)
//  - writers use plain cached stores; the barrier's RELEASE fence emits
//    buffer_wbl2 (write back dirty lines) but never buffer_inv
//  - weights / prep data: normal cached loads (kernel-boundary visibility)
// ---------------------------------------------------------------------------
__device__ __forceinline__ ull cload8(const void* p) {
    return __hip_atomic_load((const ull*)p, __ATOMIC_RELAXED, __HIP_MEMORY_SCOPE_SYSTEM);
}
__device__ __forceinline__ float2 cloadf2(const float* p) {
    union { ull u; float2 f; } c; c.u = cload8(p); return c.f;
}
__device__ __forceinline__ unsigned short f2bfu(float v) {
    bf16 h = __float2bfloat16(v);
    union { bf16 b; unsigned short s; } c; c.b = h; return c.s;
}
__device__ __forceinline__ float sigf(float x) { return 1.f / (1.f + __expf(-x)); }

// Two-level grid barrier: 8 level-1 counters (32 arrivals each, parallel RMW
// chains) -> 8-way level-2 -> monotonic epoch flag. Release fence = wbl2 only.
// bstate: [0..7] L1 counters, [8] L2 counter, [9] epoch.
__device__ __forceinline__ void gbar(int* bs, int ep) {
    __syncthreads();
    if (threadIdx.x == 0) {
        __builtin_amdgcn_fence(__ATOMIC_RELEASE, "agent");   // waitcnt + buffer_wbl2
        int* c1 = bs + (blockIdx.x & (GRPS - 1));
        if (__hip_atomic_fetch_add(c1, 1, __ATOMIC_RELAXED, __HIP_MEMORY_SCOPE_AGENT) == GSIZE - 1) {
            __hip_atomic_store(c1, 0, __ATOMIC_RELAXED, __HIP_MEMORY_SCOPE_AGENT);
            if (__hip_atomic_fetch_add(bs + 8, 1, __ATOMIC_RELAXED, __HIP_MEMORY_SCOPE_AGENT) == GRPS - 1) {
                __hip_atomic_store(bs + 8, 0, __ATOMIC_RELAXED, __HIP_MEMORY_SCOPE_AGENT);
                __hip_atomic_store(bs + 9, ep, __ATOMIC_RELAXED, __HIP_MEMORY_SCOPE_AGENT);
            }
        }
        while (__hip_atomic_load(bs + 9, __ATOMIC_RELAXED, __HIP_MEMORY_SCOPE_AGENT) < ep) {
            __builtin_amdgcn_s_sleep(2);
        }
    }
    __syncthreads();   // also a compiler ordering point for the data loads below
}

// ---------------------------------------------------------------------------
// 64x64 BT-GEMM tile: C[m0:+64, n0:+64] = A[.,K] @ B[.,K]^T, K = nch*64.
// A read via coherent 8B loads (intra-kernel data), 2-chunk-deep register
// prefetch to hide ~800cy L3 latency; B via normal cached 16B loads (weights,
// L2-resident). LDS XOR-swizzled (G4). MFMA 16x16x32 bf16; C/D layout
// col=lane&15, row=(lane>>4)*4+reg (m89-verified; proven in R2).
// EPI: 0 = f32 store, 1 = f32+bias[n], 2 = bf16 store (prep use).
// ---------------------------------------------------------------------------
template<int EPI>
__device__ void gemm64c(const bf16* __restrict__ A, int lda,
                        const bf16* __restrict__ B, int ldb,
                        void* __restrict__ Cout, long ldc, int m0, int n0,
                        int nch, const float* __restrict__ bias,
                        char* ldsA, char* ldsB)
{
    const int tid = threadIdx.x, wave = tid >> 6, lane = tid & 63;
    const int r15 = lane & 15, kg = lane >> 4;
    const int s1v = tid + 256;
    const int row0 = tid >> 3, cg0 = tid & 7;
    const int row1 = s1v >> 3, cg1 = s1v & 7;
    const int lb0 = (tid * 16) ^ ((row0 & 7) << 4);
    const int lb1 = (s1v * 16) ^ ((row1 & 7) << 4);
    const bf16* a0 = A + (size_t)(m0 + row0) * lda + cg0 * 8;
    const bf16* a1 = A + (size_t)(m0 + row1) * lda + cg1 * 8;
    const bf16* b0 = B + (size_t)(n0 + row0) * ldb + cg0 * 8;
    const bf16* b1 = B + (size_t)(n0 + row1) * ldb + cg1 * 8;

    f32x4 acc[4];
#pragma unroll
    for (int i = 0; i < 4; ++i) acc[i] = (f32x4){0.f, 0.f, 0.f, 0.f};

    // A prefetch depth 2 (chunks c, c+1 in regs), B depth 1.
    ull A0a = cload8(a0),     A0b = cload8(a0 + 4);
    ull A1a = cload8(a1),     A1b = cload8(a1 + 4);
    const int cp = (nch > 1) ? 1 : 0;
    ull A2a = cload8(a0 + cp * 64), A2b = cload8(a0 + cp * 64 + 4);
    ull A3a = cload8(a1 + cp * 64), A3b = cload8(a1 + cp * 64 + 4);
    short8 Bp0 = *(const short8*)b0, Bp1 = *(const short8*)b1;

    for (int c = 0; c < nch; ++c) {
        __syncthreads();                       // prev chunk's readers done
        *(ull*)(ldsA + lb0) = A0a; *(ull*)(ldsA + lb0 + 8) = A0b;
        *(ull*)(ldsA + lb1) = A1a; *(ull*)(ldsA + lb1 + 8) = A1b;
        *(short8*)(ldsB + lb0) = Bp0; *(short8*)(ldsB + lb1) = Bp1;
        A0a = A2a; A0b = A2b; A1a = A3a; A1b = A3b;
        const int c2 = (c + 2 < nch) ? c + 2 : nch - 1;
        A2a = cload8(a0 + c2 * 64); A2b = cload8(a0 + c2 * 64 + 4);
        A3a = cload8(a1 + c2 * 64); A3b = cload8(a1 + c2 * 64 + 4);
        const int cb = (c + 1 < nch) ? c + 1 : nch - 1;
        Bp0 = *(const short8*)(b0 + cb * 64); Bp1 = *(const short8*)(b1 + cb * 64);
        __syncthreads();
        const int bro = wave * 16 + r15;
        const int bsz = (bro & 7) << 4;
#pragma unroll
        for (int kk = 0; kk < 2; ++kk) {
            short8 bfr = *(short8*)(ldsB + ((bro * 128 + (kg + kk * 4) * 16) ^ bsz));
#pragma unroll
            for (int mf = 0; mf < 4; ++mf) {
                int aro = mf * 16 + r15;
                short8 afr = *(short8*)(ldsA + ((aro * 128 + (kg + kk * 4) * 16) ^ ((aro & 7) << 4)));
                acc[mf] = __builtin_amdgcn_mfma_f32_16x16x32_bf16(afr, bfr, acc[mf], 0, 0, 0);
            }
        }
    }
    const int col = lane & 15, rg = lane >> 4;
#pragma unroll
    for (int mf = 0; mf < 4; ++mf)
#pragma unroll
        for (int r = 0; r < 4; ++r) {
            long m = m0 + mf * 16 + rg * 4 + r;
            long n = n0 + wave * 16 + col;
            if constexpr (EPI == 0)      ((float*)Cout)[m * ldc + n] = acc[mf][r];
            else if constexpr (EPI == 1) ((float*)Cout)[m * ldc + n] = acc[mf][r] + bias[n];
            else                         ((bf16*)Cout)[m * ldc + n] = __float2bfloat16(acc[mf][r]);
        }
}

// ---------------------------------------------------------------------------
// Prep kernels (once per launch; all data re-derived each launch)
// ---------------------------------------------------------------------------
__global__ void prep_transpose(const float* __restrict__ cond, const float* __restrict__ zs,
                               float* __restrict__ condT, float* __restrict__ zsT, int* bstate) {
    int i = blockIdx.x * 256 + threadIdx.x;
    if (i < 128 * 256) {
        int b = i >> 8, c = i & 255;
        condT[c * 128 + b] = cond[i];
        zsT[c * 128 + b]   = zs[i];
    }
    if (blockIdx.x == 0 && threadIdx.x < 64) bstate[threadIdx.x] = 0;
}

__global__ void prep_wcvt(const float* __restrict__ whh1, const float* __restrict__ wih2,
                          const float* __restrict__ whh2, const float* __restrict__ wih1,
                          const float* __restrict__ headw,
                          bf16* whh1b, bf16* wih2b, bf16* whh2b, bf16* w1xb,
                          bf16* headb, bf16* headTb) {
    int gs = gridDim.x * blockDim.x;
    for (int i = blockIdx.x * blockDim.x + threadIdx.x; i < 3072 * 1024; i += gs) {
        whh1b[i] = __float2bfloat16(whh1[i]);
        wih2b[i] = __float2bfloat16(wih2[i]);
        whh2b[i] = __float2bfloat16(whh2[i]);
    }
    for (int i = blockIdx.x * blockDim.x + threadIdx.x; i < 3072 * 256; i += gs) {
        int g = i >> 8, k = i & 255;
        w1xb[i] = __float2bfloat16(wih1[g * 512 + k]);   // w_ih1[:, :256]
    }
    for (int i = blockIdx.x * blockDim.x + threadIdx.x; i < 256 * 1024; i += gs) {
        headb[i] = __float2bfloat16(headw[i]);           // [256 rows x 1024 K]
    }
    for (int i = blockIdx.x * blockDim.x + threadIdx.x; i < 1024 * 256; i += gs) {
        int j = i >> 8, l = i & 255;
        headTb[i] = __float2bfloat16(headw[l * 1024 + j]);  // headT[j][l]
    }
}

// cw[g] = sum_l b_head[l] * w1x[g][l]
__global__ void prep_cw(const float* __restrict__ wih1, const float* __restrict__ bhead,
                        float* __restrict__ cw) {
    int g = blockIdx.x * 256 + threadIdx.x;
    if (g >= 3072) return;
    float acc = 0.f;
    for (int l = 0; l < 256; ++l) acc += bhead[l] * wih1[g * 512 + l];
    cw[g] = acc;
}

// const1 = b_ih1 + cond @ w_ih1[:,256:]^T ; const1c = const1 + cw ; FiLM.
__global__ void prep_cond(const float* __restrict__ condT, const float* __restrict__ wih1,
                          const float* __restrict__ bih1, const float* __restrict__ filmw,
                          const float* __restrict__ filmb, const float* __restrict__ cw,
                          float* const1, float* const1c, float* scale, float* beta) {
    int gs = gridDim.x * blockDim.x;
    for (int idx = blockIdx.x * blockDim.x + threadIdx.x; idx < 128 * 3072; idx += gs) {
        int b = idx & 127, g = idx >> 7;
        float acc = bih1[g];
        for (int c = 0; c < 256; ++c) acc += condT[c * 128 + b] * wih1[g * 512 + 256 + c];
        const1[b * 3072 + g]  = acc;
        const1c[b * 3072 + g] = acc + cw[g];
    }
    for (int idx = blockIdx.x * blockDim.x + threadIdx.x; idx < 128 * 2048; idx += gs) {
        int b = idx & 127, jj = idx >> 7;
        float acc = filmb[jj];
        for (int c = 0; c < 256; ++c) acc += condT[c * 128 + b] * filmw[jj * 256 + c];
        if (jj < 1024) scale[b * 1024 + jj] = 1.f + acc;
        else           beta[b * 1024 + (jj - 1024)] = acc;
    }
}

// bufP0[b][g] = sum_l z_start[b][l] * w1x[g][l]  (t=0 input-gate term, f32)
__global__ void prep_px(const float* __restrict__ zsT, const float* __restrict__ wih1,
                        float* __restrict__ bufP0) {
    int gs = gridDim.x * blockDim.x;
    for (int idx = blockIdx.x * blockDim.x + threadIdx.x; idx < 128 * 3072; idx += gs) {
        int b = idx & 127, g = idx >> 7;
        float acc = 0.f;
        for (int l = 0; l < 256; ++l) acc += zsT[l * 128 + b] * wih1[g * 512 + l];
        bufP0[b * 3072 + g] = acc;
    }
}

// Wcombo[3072x1024] = w1x[3072x256] @ headT[1024x256]^T, bf16 out (MFMA).
__global__ __launch_bounds__(256) void prep_wcombo(const bf16* __restrict__ w1xb,
                                                   const bf16* __restrict__ headTb,
                                                   bf16* __restrict__ wcombob) {
    __shared__ char lds[16384];
    int v = blockIdx.x;                        // 768 tiles = 48 m x 16 n
    gemm64c<2>(w1xb, 256, headTb, 256, wcombob, 1024,
               (v % 48) * 64, (v / 48) * 64, 4, nullptr, lds, lds + 8192);
}

__global__ void prep_h0a(const float* __restrict__ zsT, const float* __restrict__ w1,
                         const float* __restrict__ b1, float* __restrict__ L1T) {
    int idx = blockIdx.x * 256 + threadIdx.x;
    if (idx >= 128 * 1024) return;
    int b = idx & 127, j = idx >> 7;
    float acc = b1[j];
    for (int k = 0; k < 256; ++k) acc += zsT[k * 128 + b] * w1[j * 256 + k];
    L1T[j * 128 + b] = fmaxf(acc, 0.f);
}

__global__ void prep_h0b(const float* __restrict__ L1T, const float* __restrict__ w2,
                         const float* __restrict__ b2,
                         float* h1, float* h2, bf16* hb1, bf16* hb2) {
    int idx = blockIdx.x * 256 + threadIdx.x;
    if (idx >= 128 * 1024) return;
    int b = idx & 127, j = idx >> 7;
    float acc = b2[j];
    for (int k = 0; k < 1024; ++k) acc += L1T[k * 128 + b] * w2[j * 1024 + k];
    h1[b * 1024 + j] = acc;
    h2[b * 1024 + j] = acc;
    bf16 hv = __float2bfloat16(acc);
    hb1[b * 1024 + j] = hv;
    hb2[b * 1024 + j] = hv;
}

// ---------------------------------------------------------------------------
// Persistent rollout: 4 phases/step.
//  A: bufQ = h1@whh1^T (96) | bufP = y@Wcombo^T (96, t>0) | dout[t-1] = y@head^T+b (8, t>0)
//  B: combine1 -> h1, hb1
//  C: bufS = h1'@wih2^T (96) | bufR = h2@whh2^T (96)
//  D: combine2 -> h2, hb2, y
// ---------------------------------------------------------------------------
struct RArgs {
    const float* bhh1; const float* bih2; const float* bhh2; const float* bheadp;
    float* const1; float* const1c; float* bufP0;
    float* scale; float* beta;
    float* h1; float* h2;
    float* bufP; float* bufQ; float* bufR; float* bufS;
    bf16* hb1; bf16* hb2; bf16* yb;
    const bf16* whh1b; const bf16* wih2b; const bf16* whh2b;
    const bf16* wcombob; const bf16* headb;
    float* dout;
    int* bstate;
};

__global__ __launch_bounds__(NT, 2) void rollout(RArgs a) {
    __shared__ char lds[16384];
    char* ldsA = lds;
    char* ldsB = lds + 8192;
    const int u = blockIdx.x, tid = threadIdx.x;
    int ep = 0;

    for (int t = 0; t < TSTEPS; ++t) {
        // ---- Phase A
        if (u < 96) {
            gemm64c<0>(a.hb1, 1024, a.whh1b, 1024, a.bufQ, 3072,
                       (u & 1) * 64, (u >> 1) * 64, 16, nullptr, ldsA, ldsB);
        } else if (u < 192) {
            if (t > 0) { int v = u - 96;
                gemm64c<0>(a.yb, 1024, a.wcombob, 1024, a.bufP, 3072,
                           (v & 1) * 64, (v >> 1) * 64, 16, nullptr, ldsA, ldsB); }
        } else if (u < 200) {
            if (t > 0) { int v = u - 192;
                gemm64c<1>(a.yb, 1024, a.headb, 1024, a.dout + (size_t)(t - 1) * 256, 131072,
                           (v & 1) * 64, (v >> 1) * 64, 16, a.bheadp, ldsA, ldsB); }
        }
        gbar(a.bstate, ++ep);

        // ---- Phase B: combine1 (65536 threads x 2 elems)
        {
            int g2 = u * NT + tid;
            int b = g2 >> 9;
            int j = (g2 & 511) << 1;
            long base = (long)b * 3072 + j;
            long hb = (long)b * 1024 + j;
            const float* gip  = (t == 0) ? a.bufP0  : a.bufP;
            const float* cadd = (t == 0) ? a.const1 : a.const1c;
            float2 pr = cloadf2(gip + base);
            float2 pz = cloadf2(gip + base + 1024);
            float2 pn = cloadf2(gip + base + 2048);
            float2 qr = cloadf2(a.bufQ + base);
            float2 qz = cloadf2(a.bufQ + base + 1024);
            float2 qn = cloadf2(a.bufQ + base + 2048);
            float2 cr = *(const float2*)(cadd + base);
            float2 cz = *(const float2*)(cadd + base + 1024);
            float2 cn = *(const float2*)(cadd + base + 2048);
            float2 br = *(const float2*)(a.bhh1 + j);
            float2 bz = *(const float2*)(a.bhh1 + j + 1024);
            float2 bn = *(const float2*)(a.bhh1 + j + 2048);
            float2 ho = *(const float2*)(a.h1 + hb);
            float r0 = sigf(pr.x + cr.x + qr.x + br.x);
            float r1 = sigf(pr.y + cr.y + qr.y + br.y);
            float z0 = sigf(pz.x + cz.x + qz.x + bz.x);
            float z1 = sigf(pz.y + cz.y + qz.y + bz.y);
            float n0 = tanhf(pn.x + cn.x + r0 * (qn.x + bn.x));
            float n1 = tanhf(pn.y + cn.y + r1 * (qn.y + bn.y));
            float hp0 = (1.f - z0) * n0 + z0 * ho.x;
            float hp1 = (1.f - z1) * n1 + z1 * ho.y;
            *(float2*)(a.h1 + hb) = make_float2(hp0, hp1);
            *(unsigned*)((unsigned short*)a.hb1 + hb) =
                (unsigned)f2bfu(hp0) | ((unsigned)f2bfu(hp1) << 16);
        }
        gbar(a.bstate, ++ep);

        // ---- Phase C
        if (u < 96) {
            gemm64c<0>(a.hb1, 1024, a.wih2b, 1024, a.bufS, 3072,
                       (u & 1) * 64, (u >> 1) * 64, 16, nullptr, ldsA, ldsB);
        } else if (u < 192) {
            int v = u - 96;
            gemm64c<0>(a.hb2, 1024, a.whh2b, 1024, a.bufR, 3072,
                       (v & 1) * 64, (v >> 1) * 64, 16, nullptr, ldsA, ldsB);
        }
        gbar(a.bstate, ++ep);

        // ---- Phase D: combine2
        {
            int g2 = u * NT + tid;
            int b = g2 >> 9;
            int j = (g2 & 511) << 1;
            long base = (long)b * 3072 + j;
            long hb = (long)b * 1024 + j;
            float2 pr = cloadf2(a.bufS + base);
            float2 pz = cloadf2(a.bufS + base + 1024);
            float2 pn = cloadf2(a.bufS + base + 2048);
            float2 qr = cloadf2(a.bufR + base);
            float2 qz = cloadf2(a.bufR + base + 1024);
            float2 qn = cloadf2(a.bufR + base + 2048);
            float2 cr = *(const float2*)(a.bih2 + j);
            float2 cz = *(const float2*)(a.bih2 + j + 1024);
            float2 cn = *(const float2*)(a.bih2 + j + 2048);
            float2 br = *(const float2*)(a.bhh2 + j);
            float2 bz = *(const float2*)(a.bhh2 + j + 1024);
            float2 bn = *(const float2*)(a.bhh2 + j + 2048);
            float2 ho = *(const float2*)(a.h2 + hb);
            float r0 = sigf(pr.x + cr.x + qr.x + br.x);
            float r1 = sigf(pr.y + cr.y + qr.y + br.y);
            float z0 = sigf(pz.x + cz.x + qz.x + bz.x);
            float z1 = sigf(pz.y + cz.y + qz.y + bz.y);
            float n0 = tanhf(pn.x + cn.x + r0 * (qn.x + bn.x));
            float n1 = tanhf(pn.y + cn.y + r1 * (qn.y + bn.y));
            float hp0 = (1.f - z0) * n0 + z0 * ho.x;
            float hp1 = (1.f - z1) * n1 + z1 * ho.y;
            *(float2*)(a.h2 + hb) = make_float2(hp0, hp1);
            *(unsigned*)((unsigned short*)a.hb2 + hb) =
                (unsigned)f2bfu(hp0) | ((unsigned)f2bfu(hp1) << 16);
            float2 sc = *(const float2*)(a.scale + hb);
            float2 be = *(const float2*)(a.beta + hb);
            float y0 = sc.x * hp0 + be.x;
            float y1 = sc.y * hp1 + be.y;
            *(unsigned*)((unsigned short*)a.yb + hb) =
                (unsigned)f2bfu(y0) | ((unsigned)f2bfu(y1) << 16);
        }
        gbar(a.bstate, ++ep);
    }

    // final output row: dout[511] = y(511) @ head^T + bias
    if (u >= 192 && u < 200) {
        int v = u - 192;
        gemm64c<1>(a.yb, 1024, a.headb, 1024, a.dout + (size_t)511 * 256, 131072,
                   (v & 1) * 64, (v >> 1) * 64, 16, a.bheadp, ldsA, ldsB);
    }
}

// ---------------------------------------------------------------------------
extern "C" void kernel_launch(void* const* d_in, const int* in_sizes, int n_in,
                              void* d_out, int out_size, void* d_ws, size_t ws_size,
                              hipStream_t stream) {
    const float* zs       = (const float*)d_in[0];
    const float* cond     = (const float*)d_in[1];
    // d_in[2] = max_len (fixed 512)
    const float* z2hw1    = (const float*)d_in[3];
    const float* z2hb1    = (const float*)d_in[4];
    const float* z2hw2    = (const float*)d_in[5];
    const float* z2hb2    = (const float*)d_in[6];
    const float* wih1     = (const float*)d_in[7];
    const float* whh1     = (const float*)d_in[8];
    const float* bih1     = (const float*)d_in[9];
    const float* bhh1     = (const float*)d_in[10];
    const float* wih2     = (const float*)d_in[11];
    const float* whh2     = (const float*)d_in[12];
    const float* bih2     = (const float*)d_in[13];
    const float* bhh2     = (const float*)d_in[14];
    const float* filmw    = (const float*)d_in[15];
    const float* filmb    = (const float*)d_in[16];
    const float* headw    = (const float*)d_in[17];
    const float* headbias = (const float*)d_in[18];

    char* p = (char*)d_ws;
    auto alloc = [&](size_t bytes) {
        char* r = p;
        p += (bytes + 255) & ~(size_t)255;
        return r;
    };
    int*  bstate   = (int*)alloc(256);
    bf16* whh1b    = (bf16*)alloc(3072 * 1024 * 2);
    bf16* wih2b    = (bf16*)alloc(3072 * 1024 * 2);
    bf16* whh2b    = (bf16*)alloc(3072 * 1024 * 2);
    bf16* wcombob  = (bf16*)alloc(3072 * 1024 * 2);
    bf16* w1xb     = (bf16*)alloc(3072 * 256 * 2);
    bf16* headb    = (bf16*)alloc(256 * 1024 * 2);
    bf16* headTb   = (bf16*)alloc(1024 * 256 * 2);
    float* cw      = (float*)alloc(3072 * 4);
    float* const1  = (float*)alloc(128 * 3072 * 4);
    float* const1c = (float*)alloc(128 * 3072 * 4);
    float* bufP0   = (float*)alloc(128 * 3072 * 4);
    float* scale   = (float*)alloc(128 * 1024 * 4);
    float* beta    = (float*)alloc(128 * 1024 * 4);
    float* h1      = (float*)alloc(128 * 1024 * 4);
    float* h2      = (float*)alloc(128 * 1024 * 4);
    float* bufP    = (float*)alloc(128 * 3072 * 4);
    float* bufQ    = (float*)alloc(128 * 3072 * 4);
    float* bufR    = (float*)alloc(128 * 3072 * 4);
    float* bufS    = (float*)alloc(128 * 3072 * 4);
    bf16* hb1      = (bf16*)alloc(128 * 1024 * 2);
    bf16* hb2      = (bf16*)alloc(128 * 1024 * 2);
    bf16* yb       = (bf16*)alloc(128 * 1024 * 2);
    float* condT   = (float*)alloc(128 * 256 * 4);
    float* zsT     = (float*)alloc(128 * 256 * 4);
    float* L1T     = (float*)alloc(128 * 1024 * 4);
    // total ~43 MiB of d_ws

    prep_transpose<<<dim3(128), dim3(256), 0, stream>>>(cond, zs, condT, zsT, bstate);
    prep_wcvt<<<dim3(1024), dim3(256), 0, stream>>>(whh1, wih2, whh2, wih1, headw,
                                                    whh1b, wih2b, whh2b, w1xb, headb, headTb);
    prep_cw<<<dim3(12), dim3(256), 0, stream>>>(wih1, headbias, cw);
    prep_cond<<<dim3(1536), dim3(256), 0, stream>>>(condT, wih1, bih1, filmw, filmb, cw,
                                                    const1, const1c, scale, beta);
    prep_px<<<dim3(1536), dim3(256), 0, stream>>>(zsT, wih1, bufP0);
    prep_wcombo<<<dim3(768), dim3(256), 0, stream>>>(w1xb, headTb, wcombob);
    prep_h0a<<<dim3(512), dim3(256), 0, stream>>>(zsT, z2hw1, z2hb1, L1T);
    prep_h0b<<<dim3(512), dim3(256), 0, stream>>>(L1T, z2hw2, z2hb2, h1, h2, hb1, hb2);

    RArgs ra;
    ra.bhh1 = bhh1; ra.bih2 = bih2; ra.bhh2 = bhh2; ra.bheadp = headbias;
    ra.const1 = const1; ra.const1c = const1c; ra.bufP0 = bufP0;
    ra.scale = scale; ra.beta = beta;
    ra.h1 = h1; ra.h2 = h2;
    ra.bufP = bufP; ra.bufQ = bufQ; ra.bufR = bufR; ra.bufS = bufS;
    ra.hb1 = hb1; ra.hb2 = hb2; ra.yb = yb;
    ra.whh1b = whh1b; ra.wih2b = wih2b; ra.whh2b = whh2b;
    ra.wcombob = wcombob; ra.headb = headb;
    ra.dout = (float*)d_out;
    ra.bstate = bstate;

    rollout<<<dim3(NB), dim3(NT), 0, stream>>>(ra);
}

// Round 4
// 32619.751 us; speedup vs baseline: 3.4449x; 1.3459x over previous
//
#include <hip/hip_runtime.h>
#include <hip/hip_bf16.h>

typedef __attribute__((ext_vector_type(8))) short short8;
typedef __attribute__((ext_vector_type(4))) float f32x4;
typedef __hip_bfloat16 bf16;
typedef unsigned long long ull;

#define NB 256
#define NT 256
#define TSTEPS 512

// ---------------------------------------------------------------------------
// Coherence protocol v3 (no fences, no L2 invalidation, no L2 dirty lines):
//  - cross-block intra-kernel data: system-scope relaxed atomic STORES
//    (write-through to coherence point/L3, no L2 allocation) and system-scope
//    relaxed atomic LOADS (bypass stale L2). Barrier only needs vmcnt drain
//    (__syncthreads) before the arrival atomic — no cache fence at all.
//  - weights/prep constants: plain cached loads, L2-resident (XCD-stable
//    tile mapping keeps per-XCD weight footprint ~3.1 MB < 4 MB L2).
//  - h1/h2: block-private across steps -> plain cached load/store.
// ---------------------------------------------------------------------------
__device__ __forceinline__ ull cload8(const void* p) {
    return __hip_atomic_load((const ull*)p, __ATOMIC_RELAXED, __HIP_MEMORY_SCOPE_SYSTEM);
}
__device__ __forceinline__ float2 cloadf2(const float* p) {
    union { ull u; float2 f; } c; c.u = cload8(p); return c.f;
}
__device__ __forceinline__ void sysst4f(float* p, float v) {
    __hip_atomic_store(p, v, __ATOMIC_RELAXED, __HIP_MEMORY_SCOPE_SYSTEM);
}
__device__ __forceinline__ void sysst4u(unsigned* p, unsigned v) {
    __hip_atomic_store(p, v, __ATOMIC_RELAXED, __HIP_MEMORY_SCOPE_SYSTEM);
}
__device__ __forceinline__ unsigned short f2bfu(float v) {
    bf16 h = __float2bfloat16(v);
    union { bf16 b; unsigned short s; } c; c.b = h; return c.s;
}
__device__ __forceinline__ float sigf(float x) { return 1.f / (1.f + __expf(-x)); }

// Two-level grid barrier, 16 L1 counters x 16 arrivals -> 1 L2 counter ->
// monotonic epoch. No cache fences (protocol v3). bs[0..15] L1, bs[16] L2,
// bs[17] epoch.
__device__ __forceinline__ void gbar(int* bs, int ep) {
    __syncthreads();                     // drains vmcnt: all stores acked at L3
    if (threadIdx.x == 0) {
        int* c1 = bs + (blockIdx.x & 15);
        if (__hip_atomic_fetch_add(c1, 1, __ATOMIC_RELAXED, __HIP_MEMORY_SCOPE_AGENT) == 15) {
            __hip_atomic_store(c1, 0, __ATOMIC_RELAXED, __HIP_MEMORY_SCOPE_AGENT);
            if (__hip_atomic_fetch_add(bs + 16, 1, __ATOMIC_RELAXED, __HIP_MEMORY_SCOPE_AGENT) == 15) {
                __hip_atomic_store(bs + 16, 0, __ATOMIC_RELAXED, __HIP_MEMORY_SCOPE_AGENT);
                __hip_atomic_store(bs + 17, ep, __ATOMIC_RELAXED, __HIP_MEMORY_SCOPE_AGENT);
            }
        }
        while (__hip_atomic_load(bs + 17, __ATOMIC_RELAXED, __HIP_MEMORY_SCOPE_AGENT) < ep) {
            __builtin_amdgcn_s_sleep(2);
        }
    }
    __syncthreads();                     // compiler ordering point for data loads
}

// XCD-stable mapping for 96-tile jobs (2 m x 48 n): block->XCD is u%8, so
// give XCD x both m-tiles of n-slices [6x, 6x+6) => per-XCD slice set is
// identical every step and ~768 KB per weight matrix.
__device__ __forceinline__ void map96(int v, int& m0, int& n0) {
    int x = v & 7, r = v >> 3;
    n0 = (x * 6 + (r >> 1)) * 64;
    m0 = (r & 1) * 64;
}

// ---------------------------------------------------------------------------
// 64x64 BT-GEMM tile: C[m0:+64, n0:+64] = A[.,K] @ B[.,K]^T, K = nch*64.
// A: system-scope loads (intra-kernel data), prefetch depth 3 (named regs,
// rule #20). B: cached loads (L2-resident weights), depth 2. LDS double-
// buffered (32 KB) -> ONE __syncthreads per chunk. XOR-swizzled LDS (G4).
// MFMA 16x16x32 bf16; C/D col=lane&15, row=(lane>>4)*4+reg (m89-verified).
// EPI: 0 = f32 system store, 1 = f32+bias system store, 2 = bf16 plain (prep).
// ---------------------------------------------------------------------------
template<int EPI>
__device__ void gemm64c(const bf16* __restrict__ A, int lda,
                        const bf16* __restrict__ B, int ldb,
                        void* __restrict__ Cout, long ldc, int m0, int n0,
                        int nch, const float* __restrict__ bias, char* lds)
{
    const int tid = threadIdx.x, wave = tid >> 6, lane = tid & 63;
    const int r15 = lane & 15, kg = lane >> 4;
    const int s1v = tid + 256;
    const int row0 = tid >> 3, cg0 = tid & 7;
    const int row1 = s1v >> 3, cg1 = s1v & 7;
    const int lb0 = (tid * 16) ^ ((row0 & 7) << 4);
    const int lb1 = (s1v * 16) ^ ((row1 & 7) << 4);
    const bf16* a0 = A + (size_t)(m0 + row0) * lda + cg0 * 8;
    const bf16* a1 = A + (size_t)(m0 + row1) * lda + cg1 * 8;
    const bf16* b0 = B + (size_t)(n0 + row0) * ldb + cg0 * 8;
    const bf16* b1 = B + (size_t)(n0 + row1) * ldb + cg1 * 8;

    f32x4 acc[4];
#pragma unroll
    for (int i = 0; i < 4; ++i) acc[i] = (f32x4){0.f, 0.f, 0.f, 0.f};

    // Software pipeline, explicitly rotated named regs (static indexing).
    const int k1 = (nch > 1) ? 64 : 0, k2 = (nch > 2) ? 128 : 0;
    ull A00 = cload8(a0),      A01 = cload8(a0 + 4);
    ull A02 = cload8(a1),      A03 = cload8(a1 + 4);
    ull A10 = cload8(a0 + k1), A11 = cload8(a0 + k1 + 4);
    ull A12 = cload8(a1 + k1), A13 = cload8(a1 + k1 + 4);
    ull A20 = cload8(a0 + k2), A21 = cload8(a0 + k2 + 4);
    ull A22 = cload8(a1 + k2), A23 = cload8(a1 + k2 + 4);
    short8 B00 = *(const short8*)b0,        B01 = *(const short8*)b1;
    short8 B10 = *(const short8*)(b0 + k1), B11 = *(const short8*)(b1 + k1);

    for (int c = 0; c < nch; ++c) {
        char* LA = lds + ((c & 1) << 14);
        char* LB = LA + 8192;
        *(ull*)(LA + lb0) = A00; *(ull*)(LA + lb0 + 8) = A01;
        *(ull*)(LA + lb1) = A02; *(ull*)(LA + lb1 + 8) = A03;
        *(short8*)(LB + lb0) = B00; *(short8*)(LB + lb1) = B01;
        A00 = A10; A01 = A11; A02 = A12; A03 = A13;
        A10 = A20; A11 = A21; A12 = A22; A13 = A23;
        const int c3 = (c + 3 < nch) ? (c + 3) * 64 : (nch - 1) * 64;
        A20 = cload8(a0 + c3); A21 = cload8(a0 + c3 + 4);
        A22 = cload8(a1 + c3); A23 = cload8(a1 + c3 + 4);
        B00 = B10; B01 = B11;
        const int cb = (c + 2 < nch) ? (c + 2) * 64 : (nch - 1) * 64;
        B10 = *(const short8*)(b0 + cb); B11 = *(const short8*)(b1 + cb);
        __syncthreads();                 // LDS[c&1] staged; prev buf free
        const int bro = wave * 16 + r15;
        const int bsz = (bro & 7) << 4;
#pragma unroll
        for (int kk = 0; kk < 2; ++kk) {
            short8 bfr = *(short8*)(LB + ((bro * 128 + (kg + kk * 4) * 16) ^ bsz));
#pragma unroll
            for (int mf = 0; mf < 4; ++mf) {
                int aro = mf * 16 + r15;
                short8 afr = *(short8*)(LA + ((aro * 128 + (kg + kk * 4) * 16) ^ ((aro & 7) << 4)));
                acc[mf] = __builtin_amdgcn_mfma_f32_16x16x32_bf16(afr, bfr, acc[mf], 0, 0, 0);
            }
        }
    }
    const int col = lane & 15, rg = lane >> 4;
#pragma unroll
    for (int mf = 0; mf < 4; ++mf)
#pragma unroll
        for (int r = 0; r < 4; ++r) {
            long m = m0 + mf * 16 + rg * 4 + r;
            long n = n0 + wave * 16 + col;
            if constexpr (EPI == 0)      sysst4f((float*)Cout + m * ldc + n, acc[mf][r]);
            else if constexpr (EPI == 1) sysst4f((float*)Cout + m * ldc + n, acc[mf][r] + bias[n]);
            else                         ((bf16*)Cout)[m * ldc + n] = __float2bfloat16(acc[mf][r]);
        }
}

// ---------------------------------------------------------------------------
// Prep kernels (once per launch; all state re-derived each launch)
// ---------------------------------------------------------------------------
__global__ void prep_transpose(const float* __restrict__ cond, const float* __restrict__ zs,
                               float* __restrict__ condT, float* __restrict__ zsT, int* bstate) {
    int i = blockIdx.x * 256 + threadIdx.x;
    if (i < 128 * 256) {
        int b = i >> 8, c = i & 255;
        condT[c * 128 + b] = cond[i];
        zsT[c * 128 + b]   = zs[i];
    }
    if (blockIdx.x == 0 && threadIdx.x < 64) bstate[threadIdx.x] = 0;
}

__global__ void prep_wcvt(const float* __restrict__ whh1, const float* __restrict__ wih2,
                          const float* __restrict__ whh2, const float* __restrict__ wih1,
                          const float* __restrict__ headw,
                          bf16* whh1b, bf16* wih2b, bf16* whh2b, bf16* w1xb,
                          bf16* headb, bf16* headTb) {
    int gs = gridDim.x * blockDim.x;
    for (int i = blockIdx.x * blockDim.x + threadIdx.x; i < 3072 * 1024; i += gs) {
        whh1b[i] = __float2bfloat16(whh1[i]);
        wih2b[i] = __float2bfloat16(wih2[i]);
        whh2b[i] = __float2bfloat16(whh2[i]);
    }
    for (int i = blockIdx.x * blockDim.x + threadIdx.x; i < 3072 * 256; i += gs) {
        int g = i >> 8, k = i & 255;
        w1xb[i] = __float2bfloat16(wih1[g * 512 + k]);   // w_ih1[:, :256]
    }
    for (int i = blockIdx.x * blockDim.x + threadIdx.x; i < 256 * 1024; i += gs) {
        headb[i] = __float2bfloat16(headw[i]);           // [256 x 1024]
    }
    for (int i = blockIdx.x * blockDim.x + threadIdx.x; i < 1024 * 256; i += gs) {
        int j = i >> 8, l = i & 255;
        headTb[i] = __float2bfloat16(headw[l * 1024 + j]);  // headT[j][l]
    }
}

// cw[g] = sum_l b_head[l] * w1x[g][l]
__global__ void prep_cw(const float* __restrict__ wih1, const float* __restrict__ bhead,
                        float* __restrict__ cw) {
    int g = blockIdx.x * 256 + threadIdx.x;
    if (g >= 3072) return;
    float acc = 0.f;
    for (int l = 0; l < 256; ++l) acc += bhead[l] * wih1[g * 512 + l];
    cw[g] = acc;
}

__global__ void prep_cond(const float* __restrict__ condT, const float* __restrict__ wih1,
                          const float* __restrict__ bih1, const float* __restrict__ filmw,
                          const float* __restrict__ filmb, const float* __restrict__ cw,
                          float* const1, float* const1c, float* scale, float* beta) {
    int gs = gridDim.x * blockDim.x;
    for (int idx = blockIdx.x * blockDim.x + threadIdx.x; idx < 128 * 3072; idx += gs) {
        int b = idx & 127, g = idx >> 7;
        float acc = bih1[g];
        for (int c = 0; c < 256; ++c) acc += condT[c * 128 + b] * wih1[g * 512 + 256 + c];
        const1[b * 3072 + g]  = acc;
        const1c[b * 3072 + g] = acc + cw[g];
    }
    for (int idx = blockIdx.x * blockDim.x + threadIdx.x; idx < 128 * 2048; idx += gs) {
        int b = idx & 127, jj = idx >> 7;
        float acc = filmb[jj];
        for (int c = 0; c < 256; ++c) acc += condT[c * 128 + b] * filmw[jj * 256 + c];
        if (jj < 1024) scale[b * 1024 + jj] = 1.f + acc;
        else           beta[b * 1024 + (jj - 1024)] = acc;
    }
}

// bufP0[b][g] = sum_l z_start[b][l] * w1x[g][l]  (t=0 input-gate term)
__global__ void prep_px(const float* __restrict__ zsT, const float* __restrict__ wih1,
                        float* __restrict__ bufP0) {
    int gs = gridDim.x * blockDim.x;
    for (int idx = blockIdx.x * blockDim.x + threadIdx.x; idx < 128 * 3072; idx += gs) {
        int b = idx & 127, g = idx >> 7;
        float acc = 0.f;
        for (int l = 0; l < 256; ++l) acc += zsT[l * 128 + b] * wih1[g * 512 + l];
        bufP0[b * 3072 + g] = acc;
    }
}

// Wcombo[3072x1024] = w1x[3072x256] @ headT[1024x256]^T, bf16 out.
__global__ __launch_bounds__(256) void prep_wcombo(const bf16* __restrict__ w1xb,
                                                   const bf16* __restrict__ headTb,
                                                   bf16* __restrict__ wcombob) {
    __shared__ char lds[32768];
    int v = blockIdx.x;                        // 768 tiles = 48 m x 16 n
    gemm64c<2>(w1xb, 256, headTb, 256, wcombob, 1024,
               (v % 48) * 64, (v / 48) * 64, 4, nullptr, lds);
}

__global__ void prep_h0a(const float* __restrict__ zsT, const float* __restrict__ w1,
                         const float* __restrict__ b1, float* __restrict__ L1T) {
    int idx = blockIdx.x * 256 + threadIdx.x;
    if (idx >= 128 * 1024) return;
    int b = idx & 127, j = idx >> 7;
    float acc = b1[j];
    for (int k = 0; k < 256; ++k) acc += zsT[k * 128 + b] * w1[j * 256 + k];
    L1T[j * 128 + b] = fmaxf(acc, 0.f);
}

__global__ void prep_h0b(const float* __restrict__ L1T, const float* __restrict__ w2,
                         const float* __restrict__ b2,
                         float* h1, float* h2, bf16* hb1, bf16* hb2) {
    int idx = blockIdx.x * 256 + threadIdx.x;
    if (idx >= 128 * 1024) return;
    int b = idx & 127, j = idx >> 7;
    float acc = b2[j];
    for (int k = 0; k < 1024; ++k) acc += L1T[k * 128 + b] * w2[j * 1024 + k];
    h1[b * 1024 + j] = acc;
    h2[b * 1024 + j] = acc;
    bf16 hv = __float2bfloat16(acc);
    hb1[b * 1024 + j] = hv;
    hb2[b * 1024 + j] = hv;
}

// ---------------------------------------------------------------------------
// Persistent rollout: 4 phases/step.
//  A: bufQ = h1@whh1^T | bufP = y@Wcombo^T (t>0) | dout[t-1] = y@head^T+b (t>0)
//  B: combine1 -> h1, hb1
//  C: bufS = h1'@wih2^T | bufR = h2@whh2^T
//  D: combine2 -> h2, hb2, y
// ---------------------------------------------------------------------------
struct RArgs {
    const float* bhh1; const float* bih2; const float* bhh2; const float* bheadp;
    float* const1; float* const1c; float* bufP0;
    float* scale; float* beta;
    float* h1; float* h2;
    float* bufP; float* bufQ; float* bufR; float* bufS;
    bf16* hb1; bf16* hb2; bf16* yb;
    const bf16* whh1b; const bf16* wih2b; const bf16* whh2b;
    const bf16* wcombob; const bf16* headb;
    float* dout;
    int* bstate;
};

__global__ __launch_bounds__(NT, 2) void rollout(RArgs a) {
    __shared__ char lds[32768];
    const int u = blockIdx.x, tid = threadIdx.x;
    int ep = 0;

    for (int t = 0; t < TSTEPS; ++t) {
        // ---- Phase A
        if (u < 96) {
            int m0, n0; map96(u, m0, n0);
            gemm64c<0>(a.hb1, 1024, a.whh1b, 1024, a.bufQ, 3072, m0, n0, 16, nullptr, lds);
        } else if (u < 192) {
            if (t > 0) {
                int m0, n0; map96(u - 96, m0, n0);
                gemm64c<0>(a.yb, 1024, a.wcombob, 1024, a.bufP, 3072, m0, n0, 16, nullptr, lds);
            }
        } else if (u < 200) {
            if (t > 0) {
                int v = u - 192;
                gemm64c<1>(a.yb, 1024, a.headb, 1024, a.dout + (size_t)(t - 1) * 256, 131072,
                           (v & 1) * 64, (v >> 1) * 64, 16, a.bheadp, lds);
            }
        }
        gbar(a.bstate, ++ep);

        // ---- Phase B: combine1 -> h1, hb1
        {
            int g2 = u * NT + tid;
            int b = g2 >> 9;
            int j = (g2 & 511) << 1;
            long base = (long)b * 3072 + j;
            long hb = (long)b * 1024 + j;
            const float* gip  = (t == 0) ? a.bufP0  : a.bufP;
            const float* cadd = (t == 0) ? a.const1 : a.const1c;
            float2 pr = cloadf2(gip + base);
            float2 pz = cloadf2(gip + base + 1024);
            float2 pn = cloadf2(gip + base + 2048);
            float2 qr = cloadf2(a.bufQ + base);
            float2 qz = cloadf2(a.bufQ + base + 1024);
            float2 qn = cloadf2(a.bufQ + base + 2048);
            float2 cr = *(const float2*)(cadd + base);
            float2 cz = *(const float2*)(cadd + base + 1024);
            float2 cn = *(const float2*)(cadd + base + 2048);
            float2 br = *(const float2*)(a.bhh1 + j);
            float2 bz = *(const float2*)(a.bhh1 + j + 1024);
            float2 bn = *(const float2*)(a.bhh1 + j + 2048);
            float2 ho = *(const float2*)(a.h1 + hb);
            float r0 = sigf(pr.x + cr.x + qr.x + br.x);
            float r1 = sigf(pr.y + cr.y + qr.y + br.y);
            float z0 = sigf(pz.x + cz.x + qz.x + bz.x);
            float z1 = sigf(pz.y + cz.y + qz.y + bz.y);
            float n0 = tanhf(pn.x + cn.x + r0 * (qn.x + bn.x));
            float n1 = tanhf(pn.y + cn.y + r1 * (qn.y + bn.y));
            float hp0 = (1.f - z0) * n0 + z0 * ho.x;
            float hp1 = (1.f - z1) * n1 + z1 * ho.y;
            *(float2*)(a.h1 + hb) = make_float2(hp0, hp1);
            sysst4u((unsigned*)((unsigned short*)a.hb1 + hb),
                    (unsigned)f2bfu(hp0) | ((unsigned)f2bfu(hp1) << 16));
        }
        gbar(a.bstate, ++ep);

        // ---- Phase C
        if (u < 96) {
            int m0, n0; map96(u, m0, n0);
            gemm64c<0>(a.hb1, 1024, a.wih2b, 1024, a.bufS, 3072, m0, n0, 16, nullptr, lds);
        } else if (u < 192) {
            int m0, n0; map96(u - 96, m0, n0);
            gemm64c<0>(a.hb2, 1024, a.whh2b, 1024, a.bufR, 3072, m0, n0, 16, nullptr, lds);
        }
        gbar(a.bstate, ++ep);

        // ---- Phase D: combine2 -> h2, hb2, y
        {
            int g2 = u * NT + tid;
            int b = g2 >> 9;
            int j = (g2 & 511) << 1;
            long base = (long)b * 3072 + j;
            long hb = (long)b * 1024 + j;
            float2 pr = cloadf2(a.bufS + base);
            float2 pz = cloadf2(a.bufS + base + 1024);
            float2 pn = cloadf2(a.bufS + base + 2048);
            float2 qr = cloadf2(a.bufR + base);
            float2 qz = cloadf2(a.bufR + base + 1024);
            float2 qn = cloadf2(a.bufR + base + 2048);
            float2 cr = *(const float2*)(a.bih2 + j);
            float2 cz = *(const float2*)(a.bih2 + j + 1024);
            float2 cn = *(const float2*)(a.bih2 + j + 2048);
            float2 br = *(const float2*)(a.bhh2 + j);
            float2 bz = *(const float2*)(a.bhh2 + j + 1024);
            float2 bn = *(const float2*)(a.bhh2 + j + 2048);
            float2 ho = *(const float2*)(a.h2 + hb);
            float r0 = sigf(pr.x + cr.x + qr.x + br.x);
            float r1 = sigf(pr.y + cr.y + qr.y + br.y);
            float z0 = sigf(pz.x + cz.x + qz.x + bz.x);
            float z1 = sigf(pz.y + cz.y + qz.y + bz.y);
            float n0 = tanhf(pn.x + cn.x + r0 * (qn.x + bn.x));
            float n1 = tanhf(pn.y + cn.y + r1 * (qn.y + bn.y));
            float hp0 = (1.f - z0) * n0 + z0 * ho.x;
            float hp1 = (1.f - z1) * n1 + z1 * ho.y;
            *(float2*)(a.h2 + hb) = make_float2(hp0, hp1);
            sysst4u((unsigned*)((unsigned short*)a.hb2 + hb),
                    (unsigned)f2bfu(hp0) | ((unsigned)f2bfu(hp1) << 16));
            float2 sc = *(const float2*)(a.scale + hb);
            float2 be = *(const float2*)(a.beta + hb);
            float y0 = sc.x * hp0 + be.x;
            float y1 = sc.y * hp1 + be.y;
            sysst4u((unsigned*)((unsigned short*)a.yb + hb),
                    (unsigned)f2bfu(y0) | ((unsigned)f2bfu(y1) << 16));
        }
        gbar(a.bstate, ++ep);
    }

    // final output row: dout[511] = y(511) @ head^T + bias
    if (u >= 192 && u < 200) {
        int v = u - 192;
        gemm64c<1>(a.yb, 1024, a.headb, 1024, a.dout + (size_t)511 * 256, 131072,
                   (v & 1) * 64, (v >> 1) * 64, 16, a.bheadp, lds);
    }
}

// ---------------------------------------------------------------------------
extern "C" void kernel_launch(void* const* d_in, const int* in_sizes, int n_in,
                              void* d_out, int out_size, void* d_ws, size_t ws_size,
                              hipStream_t stream) {
    const float* zs       = (const float*)d_in[0];
    const float* cond     = (const float*)d_in[1];
    // d_in[2] = max_len (fixed 512)
    const float* z2hw1    = (const float*)d_in[3];
    const float* z2hb1    = (const float*)d_in[4];
    const float* z2hw2    = (const float*)d_in[5];
    const float* z2hb2    = (const float*)d_in[6];
    const float* wih1     = (const float*)d_in[7];
    const float* whh1     = (const float*)d_in[8];
    const float* bih1     = (const float*)d_in[9];
    const float* bhh1     = (const float*)d_in[10];
    const float* wih2     = (const float*)d_in[11];
    const float* whh2     = (const float*)d_in[12];
    const float* bih2     = (const float*)d_in[13];
    const float* bhh2     = (const float*)d_in[14];
    const float* filmw    = (const float*)d_in[15];
    const float* filmb    = (const float*)d_in[16];
    const float* headw    = (const float*)d_in[17];
    const float* headbias = (const float*)d_in[18];

    char* p = (char*)d_ws;
    auto alloc = [&](size_t bytes) {
        char* r = p;
        p += (bytes + 255) & ~(size_t)255;
        return r;
    };
    int*  bstate   = (int*)alloc(256);
    bf16* whh1b    = (bf16*)alloc(3072 * 1024 * 2);
    bf16* wih2b    = (bf16*)alloc(3072 * 1024 * 2);
    bf16* whh2b    = (bf16*)alloc(3072 * 1024 * 2);
    bf16* wcombob  = (bf16*)alloc(3072 * 1024 * 2);
    bf16* w1xb     = (bf16*)alloc(3072 * 256 * 2);
    bf16* headb    = (bf16*)alloc(256 * 1024 * 2);
    bf16* headTb   = (bf16*)alloc(1024 * 256 * 2);
    float* cw      = (float*)alloc(3072 * 4);
    float* const1  = (float*)alloc(128 * 3072 * 4);
    float* const1c = (float*)alloc(128 * 3072 * 4);
    float* bufP0   = (float*)alloc(128 * 3072 * 4);
    float* scale   = (float*)alloc(128 * 1024 * 4);
    float* beta    = (float*)alloc(128 * 1024 * 4);
    float* h1      = (float*)alloc(128 * 1024 * 4);
    float* h2      = (float*)alloc(128 * 1024 * 4);
    float* bufP    = (float*)alloc(128 * 3072 * 4);
    float* bufQ    = (float*)alloc(128 * 3072 * 4);
    float* bufR    = (float*)alloc(128 * 3072 * 4);
    float* bufS    = (float*)alloc(128 * 3072 * 4);
    bf16* hb1      = (bf16*)alloc(128 * 1024 * 2);
    bf16* hb2      = (bf16*)alloc(128 * 1024 * 2);
    bf16* yb       = (bf16*)alloc(128 * 1024 * 2);
    float* condT   = (float*)alloc(128 * 256 * 4);
    float* zsT     = (float*)alloc(128 * 256 * 4);
    float* L1T     = (float*)alloc(128 * 1024 * 4);
    // total ~43 MiB of d_ws

    prep_transpose<<<dim3(128), dim3(256), 0, stream>>>(cond, zs, condT, zsT, bstate);
    prep_wcvt<<<dim3(1024), dim3(256), 0, stream>>>(whh1, wih2, whh2, wih1, headw,
                                                    whh1b, wih2b, whh2b, w1xb, headb, headTb);
    prep_cw<<<dim3(12), dim3(256), 0, stream>>>(wih1, headbias, cw);
    prep_cond<<<dim3(1536), dim3(256), 0, stream>>>(condT, wih1, bih1, filmw, filmb, cw,
                                                    const1, const1c, scale, beta);
    prep_px<<<dim3(1536), dim3(256), 0, stream>>>(zsT, wih1, bufP0);
    prep_wcombo<<<dim3(768), dim3(256), 0, stream>>>(w1xb, headTb, wcombob);
    prep_h0a<<<dim3(512), dim3(256), 0, stream>>>(zsT, z2hw1, z2hb1, L1T);
    prep_h0b<<<dim3(512), dim3(256), 0, stream>>>(L1T, z2hw2, z2hb2, h1, h2, hb1, hb2);

    RArgs ra;
    ra.bhh1 = bhh1; ra.bih2 = bih2; ra.bhh2 = bhh2; ra.bheadp = headbias;
    ra.const1 = const1; ra.const1c = const1c; ra.bufP0 = bufP0;
    ra.scale = scale; ra.beta = beta;
    ra.h1 = h1; ra.h2 = h2;
    ra.bufP = bufP; ra.bufQ = bufQ; ra.bufR = bufR; ra.bufS = bufS;
    ra.hb1 = hb1; ra.hb2 = hb2; ra.yb = yb;
    ra.whh1b = whh1b; ra.wih2b = wih2b; ra.whh2b = whh2b;
    ra.wcombob = wcombob; ra.headb = headb;
    ra.dout = (float*)d_out;
    ra.bstate = bstate;

    rollout<<<dim3(NB), dim3(NT), 0, stream>>>(ra);
}